// Round 1
// baseline (331.166 us; speedup 1.0000x reference)
//
#include <hip/hip_runtime.h>
#include <hip/hip_bf16.h>

#define BATCH 32
#define WDIM 512
#define HDIM 512
#define CDIM 3
#define KPSF 32
#define NPRED (BATCH*WDIM*HDIM*CDIM)  // 25165824

typedef __bf16 bf16x8 __attribute__((ext_vector_type(8)));
typedef float floatx16 __attribute__((ext_vector_type(16)));

// Pack psf[b,i,j,0,c] (fp32) into MFMA A-fragment order (bf16):
// dst[((c*32 + j)*2 + h)*64 + lane][t] = psf[b=lane&31][i=16h+8*(lane>>5)+t][j][c]
__global__ __launch_bounds__(64) void pack_psf(const float* __restrict__ psf,
                                               __bf16* __restrict__ dst) {
    int idx = blockIdx.x;              // [0,192) = ((c*32 + j)*2 + h)
    int h = idx & 1;
    int j = (idx >> 1) & 31;
    int c = idx >> 6;
    int lane = threadIdx.x;
    int b = lane & 31;
    int q = lane >> 5;
    bf16x8 v;
#pragma unroll
    for (int t = 0; t < 8; ++t) {
        int i = 16*h + 8*q + t;
        v[t] = (__bf16)psf[((size_t)(b*KPSF + i)*KPSF + j)*CDIM + c];
    }
    *(bf16x8*)(dst + (size_t)(idx*64 + lane)*8) = v;
}

// Block = 192 threads = 3 waves; wave w handles channel c=w of the same
// (x-set of 8 x's at stride 8, y-tile of 32). m=batch, n=y, k=i-taps.
__global__ __launch_bounds__(192, 2) void conv_mfma(
    const float* __restrict__ obs,    // [B,W,H,C]
    const float* __restrict__ img,    // [W,H,C]
    const __bf16* __restrict__ psfA,  // packed A-frags
    float* __restrict__ out)          // [B,W,H,C] pred, then loss scalar
{
    // transposed image tile: sImg[c][ylocal*88 + xlocal], rows 0..62, cols 0..87
    __shared__ __align__(16) __bf16 sImg[CDIM][63*88];

    const int tid  = threadIdx.x;
    const int lane = tid & 63;
    const int c    = tid >> 6;      // wave index = channel
    const int n    = lane & 31;     // MFMA n (y within tile) / A m (batch low 5)
    const int q    = lane >> 5;     // k-half selector within frags

    const int bx = blockIdx.x;      // [0,1024)
    const int r  = bx & 7;          // x mod-8 class
    const int g  = (bx >> 3) & 7;   // 64-wide x group
    const int yt = bx >> 6;         // y tile [0,16)
    const int x0 = g*64 + r;        // x origin; wave's x's = x0 + 8s, s=0..7
    const int ytile = yt*32;

    // ---- stage transposed image tile (zero-padded) ----
    for (int e = lane; e < 63*88; e += 64) {
        int xl = e / 63;            // column (x direction), 0..87
        int yl = e - xl*63;         // row (y direction), 0..62 -> consecutive lanes: consecutive y
        int xg = x0 + xl - 15;
        int yg = ytile + yl - 15;
        float v = 0.f;
        if ((unsigned)xg < WDIM && (unsigned)yg < HDIM)
            v = img[((size_t)xg*HDIM + yg)*CDIM + c];
        sImg[c][yl*88 + xl] = (__bf16)v;
    }
    __syncthreads();

    floatx16 acc[8] = {};

    const __bf16* pA = psfA + (size_t)c*(32*2*64*8) + (size_t)lane*8;
    const __bf16* sI = &sImg[c][q*8];   // fold q offset into base

    // ---- main loop: no barriers, pure LDS-read + MFMA ----
#pragma unroll 2
    for (int j = 0; j < 32; ++j) {
        bf16x8 A0 = *(const bf16x8*)(pA + (size_t)(j*2 + 0)*64*8);
        bf16x8 A1 = *(const bf16x8*)(pA + (size_t)(j*2 + 1)*64*8);
        const __bf16* rowp = sI + (n + j)*88;
        bf16x8 C[10];
#pragma unroll
        for (int rr = 0; rr < 10; ++rr)
            C[rr] = *(const bf16x8*)(rowp + rr*8);   // 16B-aligned ds_read_b128
#pragma unroll
        for (int s = 0; s < 8; ++s) {
            acc[s] = __builtin_amdgcn_mfma_f32_32x32x16_bf16(A0, C[s],   acc[s], 0, 0, 0);
            acc[s] = __builtin_amdgcn_mfma_f32_32x32x16_bf16(A1, C[s+2], acc[s], 0, 0, 0);
        }
    }

    // ---- epilogue: store pred, fused loss partial ----
    float ls = 0.f;
    const int y = ytile + n;
#pragma unroll
    for (int s = 0; s < 8; ++s) {
        int x = x0 + 8*s;
#pragma unroll
        for (int rr = 0; rr < 16; ++rr) {
            int b = (rr & 3) + 8*(rr >> 2) + 4*q;   // D row = batch
            size_t o = ((size_t)(b*WDIM + x)*HDIM + y)*CDIM + c;
            float p = acc[s][rr];
            out[o] = p;
            float d = obs[o] - p;
            ls += d*d;
        }
    }
#pragma unroll
    for (int m = 32; m >= 1; m >>= 1) ls += __shfl_xor(ls, m, 64);
    if (lane == 0) atomicAdd(out + NPRED, ls * (1.0f/(float)NPRED));
}

extern "C" void kernel_launch(void* const* d_in, const int* in_sizes, int n_in,
                              void* d_out, int out_size, void* d_ws, size_t ws_size,
                              hipStream_t stream) {
    const float* obs = (const float*)d_in[0];   // observed_images [32,512,512,3]
    const float* img = (const float*)d_in[1];   // estimated_image [512,512,3]
    const float* psf = (const float*)d_in[2];   // psfs [32,32,32,1,3]
    float* out = (float*)d_out;                 // pred (25165824) + loss (1)
    __bf16* psfA = (__bf16*)d_ws;               // 196608 B packed psf frags

    pack_psf<<<192, 64, 0, stream>>>(psf, psfA);
    hipMemsetAsync(out + NPRED, 0, sizeof(float), stream);
    conv_mfma<<<1024, 192, 0, stream>>>(obs, img, psfA, out);
}

// Round 2
// 269.772 us; speedup vs baseline: 1.2276x; 1.2276x over previous
//
#include <hip/hip_runtime.h>
#include <hip/hip_bf16.h>

#define BATCH 32
#define WDIM 512
#define HDIM 512
#define CDIM 3
#define KPSF 32
#define NPRED (BATCH*WDIM*HDIM*CDIM)  // 25165824

#define TW 88        // tile width  (x): 64 + 15 + 9 pad -> 8-elem aligned rows
#define TH 63        // tile height (y): 32 + 31
#define TE (TW*TH)   // 5544 per channel
#define TALL (TW*TH*CDIM)  // 16632 dense elements

typedef __bf16 bf16x8 __attribute__((ext_vector_type(8)));
typedef float floatx16 __attribute__((ext_vector_type(16)));

// Pack psf[b,i,j,0,c] (fp32) into MFMA A-fragment order (bf16):
// dst[((c*32 + j)*2 + h)*64 + lane][t] = psf[b=lane&31][i=16h+8*(lane>>5)+t][j][c]
__global__ __launch_bounds__(64) void pack_psf(const float* __restrict__ psf,
                                               __bf16* __restrict__ dst,
                                               float* __restrict__ loss) {
    if (blockIdx.x == 0 && threadIdx.x == 0) *loss = 0.f;
    int idx = blockIdx.x;              // [0,192) = ((c*32 + j)*2 + h)
    int h = idx & 1;
    int j = (idx >> 1) & 31;
    int c = idx >> 6;
    int lane = threadIdx.x;
    int b = lane & 31;
    int q = lane >> 5;
    bf16x8 v;
#pragma unroll
    for (int t = 0; t < 8; ++t) {
        int i = 16*h + 8*q + t;
        v[t] = (__bf16)psf[((size_t)(b*KPSF + i)*KPSF + j)*CDIM + c];
    }
    *(bf16x8*)(dst + (size_t)(idx*64 + lane)*8) = v;
}

// Block = 192 threads = 3 waves; wave w = channel c of the same
// (x-set of 8 x's at stride 8, y-tile of 32). MFMA m=batch, n=y, k=i-taps.
__global__ __launch_bounds__(192, 2) void conv_mfma(
    const float* __restrict__ obs,    // [B,W,H,C]
    const float* __restrict__ img,    // [W,H,C]
    const __bf16* __restrict__ psfA,  // packed A-frags
    float* __restrict__ out)          // [B,W,H,C] pred, then loss scalar
{
    // sImg (main loop) and sOut (epilogue staging) share the same LDS.
    __shared__ __align__(16) unsigned char smem[CDIM*TE*2];  // 33264 B
    __bf16 (*sImg)[TE] = (__bf16 (*)[TE])smem;
    float* sOut = (float*)smem;                               // 12288 B used

    const int tid  = threadIdx.x;
    const int lane = tid & 63;
    const int c    = tid >> 6;      // wave index = channel
    const int n    = lane & 31;     // MFMA n (y within tile)
    const int q    = lane >> 5;     // k-half selector

    const int bx = blockIdx.x;      // [0,1024)
    const int r  = bx & 7;          // x mod-8 class
    const int g  = (bx >> 3) & 7;   // 64-wide x group
    const int yt = bx >> 6;         // y tile [0,16)
    const int x0 = g*64 + r;        // wave's x's = x0 + 8s, s=0..7
    const int ytile = yt*32;

    // ---- stage transposed image tile, dense/coalesced across (x,y,c) ----
    const bool interior = (x0 >= 15) && (x0 <= WDIM - 73) &&
                          (ytile >= 15) && (ytile <= HDIM - 48);
    if (interior) {
        const float* ibase = img + ((size_t)(x0-15)*HDIM + (ytile-15))*CDIM;
#pragma unroll 4
        for (int e = tid; e < TALL; e += 192) {
            int xl = e / (TH*CDIM);
            int rr = e - xl*(TH*CDIM);
            int yl = rr / 3;
            int cc = rr - yl*3;
            float v = ibase[(size_t)xl*(HDIM*CDIM) + rr];
            sImg[cc][yl*TW + xl] = (__bf16)v;
        }
    } else {
#pragma unroll 4
        for (int e = tid; e < TALL; e += 192) {
            int xl = e / (TH*CDIM);
            int rr = e - xl*(TH*CDIM);
            int yl = rr / 3;
            int cc = rr - yl*3;
            int xg = x0 + xl - 15;
            int yg = ytile + yl - 15;
            float v = 0.f;
            if ((unsigned)xg < WDIM && (unsigned)yg < HDIM)
                v = img[((size_t)xg*HDIM + yg)*CDIM + cc];
            sImg[cc][yl*TW + xl] = (__bf16)v;
        }
    }
    __syncthreads();

    // ---- main loop: LDS reads + MFMA, A(j+1) prefetched from L2 ----
    floatx16 acc[8] = {};
    const __bf16* pA = psfA + (size_t)c*(KPSF*2*64*8) + (size_t)lane*8;
    const __bf16* sI = (const __bf16*)&sImg[c][q*8];

    bf16x8 A0 = *(const bf16x8*)(pA);
    bf16x8 A1 = *(const bf16x8*)(pA + 512);
#pragma unroll 4
    for (int j = 0; j < 32; ++j) {
        bf16x8 cA0 = A0, cA1 = A1;
        if (j < 31) {
            A0 = *(const bf16x8*)(pA + (size_t)(j+1)*1024);
            A1 = *(const bf16x8*)(pA + (size_t)(j+1)*1024 + 512);
        }
        const __bf16* rowp = sI + (n + j)*TW;
        bf16x8 C[10];
#pragma unroll
        for (int rr = 0; rr < 10; ++rr)
            C[rr] = *(const bf16x8*)(rowp + rr*8);   // 16B-aligned ds_read_b128
#pragma unroll
        for (int s = 0; s < 8; ++s) {
            acc[s] = __builtin_amdgcn_mfma_f32_32x32x16_bf16(cA0, C[s],   acc[s], 0, 0, 0);
            acc[s] = __builtin_amdgcn_mfma_f32_32x32x16_bf16(cA1, C[s+2], acc[s], 0, 0, 0);
        }
    }

    // ---- epilogue: LDS round-trip -> coalesced float4 stores + fused loss ----
    float ls = 0.f;
#pragma unroll 1
    for (int s = 0; s < 8; ++s) {
        __syncthreads();   // sImg/sOut reads of previous phase complete
#pragma unroll
        for (int rr = 0; rr < 16; ++rr) {
            int b = (rr & 3) + 8*(rr >> 2) + 4*q;   // D row = batch
            sOut[(b*32 + n)*3 + c] = acc[s][rr];    // bank = 3n+c: conflict-free
        }
        __syncthreads();
        const int x = x0 + 8*s;
#pragma unroll
        for (int k = 0; k < 4; ++k) {
            int f = tid + 192*k;                    // float4 index [0,768)
            int fb = f / 24;                        // batch
            int rem = (f - fb*24) * 4;              // offset in 96-float run
            size_t o = (((size_t)fb*WDIM + x)*HDIM + ytile)*CDIM + rem;
            float4 p = *(const float4*)&sOut[4*f];
            float4 ob = *(const float4*)&obs[o];
            *(float4*)&out[o] = p;
            float d0 = ob.x - p.x, d1 = ob.y - p.y;
            float d2 = ob.z - p.z, d3 = ob.w - p.w;
            ls += d0*d0 + d1*d1 + d2*d2 + d3*d3;
        }
    }

#pragma unroll
    for (int m = 32; m >= 1; m >>= 1) ls += __shfl_xor(ls, m, 64);
    if (lane == 0) atomicAdd(out + NPRED, ls * (1.0f/(float)NPRED));
}

extern "C" void kernel_launch(void* const* d_in, const int* in_sizes, int n_in,
                              void* d_out, int out_size, void* d_ws, size_t ws_size,
                              hipStream_t stream) {
    const float* obs = (const float*)d_in[0];   // observed_images [32,512,512,3]
    const float* img = (const float*)d_in[1];   // estimated_image [512,512,3]
    const float* psf = (const float*)d_in[2];   // psfs [32,32,32,1,3]
    float* out = (float*)d_out;                 // pred (25165824) + loss (1)
    __bf16* psfA = (__bf16*)d_ws;               // 196608 B packed psf frags

    pack_psf<<<192, 64, 0, stream>>>(psf, psfA, out + NPRED);
    conv_mfma<<<1024, 192, 0, stream>>>(obs, img, psfA, out);
}